// Round 18
// baseline (384.359 us; speedup 1.0000x reference)
//
#include <hip/hip_runtime.h>
#include <hip/hip_bf16.h>
#include <math.h>

#define B_   2
#define ND_  2048
#define NE_  2048
#define D_   1024
#define H_   16
#define HD_  64
#define DFF_ 4096
#define T_   4096   // B_*ND_ tokens

typedef __attribute__((ext_vector_type(8))) short bf16x8;
typedef __attribute__((ext_vector_type(4))) float f32x4;

#if __has_builtin(__builtin_amdgcn_exp2f)
#define EXP2(x) __builtin_amdgcn_exp2f(x)
#else
#define EXP2(x) exp2f(x)
#endif

__device__ __forceinline__ short f2bf(float f) {
  union { float f; unsigned u; } v; v.f = f;
  return (short)((v.u + 0x7FFFu + ((v.u >> 16) & 1u)) >> 16);
}
__device__ __forceinline__ float bf2f(short s) {
  union { unsigned u; float f; } v; v.u = ((unsigned)(unsigned short)s) << 16;
  return v.f;
}

typedef const __attribute__((address_space(1))) void gvoid_t;
typedef __attribute__((address_space(3))) void lvoid_t;

__device__ __forceinline__ void gload16(const void* src, void* dst) {
  __builtin_amdgcn_global_load_lds((gvoid_t*)src, (lvoid_t*)dst, 16, 0, 0);
}

// ---------------- merged weight-prep: all transposes + memory cast -----------
__global__ __launch_bounds__(256) void prep(
    const float* __restrict__ Wqkv, short* __restrict__ wqkv_t,
    const float* __restrict__ W1, short* __restrict__ w1_t,
    const float* __restrict__ W2, short* __restrict__ w2_t,
    const float* __restrict__ i0, const float* __restrict__ i1,
    const float* __restrict__ i2, const float* __restrict__ i3,
    const float* __restrict__ i4,
    short* __restrict__ o0, short* __restrict__ o1, short* __restrict__ o2,
    short* __restrict__ o3, short* __restrict__ o4,
    const float* __restrict__ mem, short* __restrict__ membf) {
  const int id = blockIdx.x;
  const int tid = threadIdx.x;
  if (id >= 16384) {  // memory cast
    const int i = (id - 16384) * 256 + tid;
    float4 v = ((const float4*)mem)[i];
    short4 o;
    o.x = f2bf(v.x); o.y = f2bf(v.y); o.z = f2bf(v.z); o.w = f2bf(v.w);
    ((short4*)membf)[i] = o;
    return;
  }
  const float* in; short* out; int K, N, bx, by;
  if (id < 3072) {
    in = Wqkv; out = wqkv_t; K = 1024; N = 3072; bx = id % 96; by = id / 96;
  } else if (id < 7168) {
    const int t = id - 3072;
    in = W1; out = w1_t; K = 1024; N = 4096; bx = t % 128; by = t / 128;
  } else if (id < 11264) {
    const int t = id - 7168;
    in = W2; out = w2_t; K = 4096; N = 1024; bx = t % 32; by = t / 32;
  } else {
    const int t = id - 11264;
    const int z = t >> 10, r = t & 1023;
    bx = r % 32; by = r / 32; K = 1024; N = 1024;
    in  = z == 0 ? i0 : z == 1 ? i1 : z == 2 ? i2 : z == 3 ? i3 : i4;
    out = z == 0 ? o0 : z == 1 ? o1 : z == 2 ? o2 : z == 3 ? o3 : o4;
  }
  __shared__ float tb[32][33];
  const int tx = tid & 31, ty = tid >> 5;
  const int n0 = bx * 32, k0 = by * 32;
#pragma unroll
  for (int i = 0; i < 4; ++i)
    tb[ty + i * 8][tx] = in[(size_t)(k0 + ty + i * 8) * N + n0 + tx];
  __syncthreads();
#pragma unroll
  for (int i = 0; i < 4; ++i)
    out[(size_t)(n0 + ty + i * 8) * K + k0 + tx] = f2bf(tb[tx][ty + i * 8]);
}

// ---------------- LayerNorm (row of 1024) fp32 -> bf16 -----------------------
__global__ __launch_bounds__(256) void ln_kernel(const float* __restrict__ x,
                                                 const float* __restrict__ g,
                                                 const float* __restrict__ b,
                                                 short* __restrict__ out) {
  const int row = blockIdx.x;
  const int tid = threadIdx.x;
  const float* xr = x + (size_t)row * D_;
  float4 v = reinterpret_cast<const float4*>(xr)[tid];
  float s  = v.x + v.y + v.z + v.w;
  float s2 = v.x * v.x + v.y * v.y + v.z * v.z + v.w * v.w;
#pragma unroll
  for (int m = 1; m < 64; m <<= 1) {
    s  += __shfl_xor(s, m);
    s2 += __shfl_xor(s2, m);
  }
  __shared__ float ss[4], ss2[4];
  const int w = tid >> 6;
  if ((tid & 63) == 0) { ss[w] = s; ss2[w] = s2; }
  __syncthreads();
  s  = ss[0] + ss[1] + ss[2] + ss[3];
  s2 = ss2[0] + ss2[1] + ss2[2] + ss2[3];
  const float mu   = s * (1.0f / D_);
  const float var  = s2 * (1.0f / D_) - mu * mu;
  const float rstd = rsqrtf(var + 1e-5f);
  float4 gv = reinterpret_cast<const float4*>(g)[tid];
  float4 bv = reinterpret_cast<const float4*>(b)[tid];
  short4 o;
  o.x = f2bf((v.x - mu) * rstd * gv.x + bv.x);
  o.y = f2bf((v.y - mu) * rstd * gv.y + bv.y);
  o.z = f2bf((v.z - mu) * rstd * gv.z + bv.z);
  o.w = f2bf((v.w - mu) * rstd * gv.w + bv.w);
  reinterpret_cast<short4*>(out + (size_t)row * D_)[tid] = o;
}

// ---------------- fused residual + bias + LayerNorm --------------------------
__global__ __launch_bounds__(256) void ln_fused(const float* __restrict__ xprev,
                                                const short* delta,
                                                const float* __restrict__ pbias,
                                                const float* __restrict__ g,
                                                const float* __restrict__ b,
                                                short* out_ln,
                                                float* __restrict__ out_x) {
  const int row = blockIdx.x;
  const int tid = threadIdx.x;
  float4 v = reinterpret_cast<const float4*>(xprev + (size_t)row * D_)[tid];
  short4 dv = reinterpret_cast<const short4*>(delta + (size_t)row * D_)[tid];
  float4 pb = reinterpret_cast<const float4*>(pbias)[tid];
  v.x += bf2f(dv.x) + pb.x;
  v.y += bf2f(dv.y) + pb.y;
  v.z += bf2f(dv.z) + pb.z;
  v.w += bf2f(dv.w) + pb.w;
  float s  = v.x + v.y + v.z + v.w;
  float s2 = v.x * v.x + v.y * v.y + v.z * v.z + v.w * v.w;
#pragma unroll
  for (int m = 1; m < 64; m <<= 1) {
    s  += __shfl_xor(s, m);
    s2 += __shfl_xor(s2, m);
  }
  __shared__ float ss[4], ss2[4];
  const int w = tid >> 6;
  if ((tid & 63) == 0) { ss[w] = s; ss2[w] = s2; }
  __syncthreads();
  s  = ss[0] + ss[1] + ss[2] + ss[3];
  s2 = ss2[0] + ss2[1] + ss2[2] + ss2[3];
  const float mu   = s * (1.0f / D_);
  const float var  = s2 * (1.0f / D_) - mu * mu;
  const float rstd = rsqrtf(var + 1e-5f);
  reinterpret_cast<float4*>(out_x + (size_t)row * D_)[tid] = v;
  float4 gv = reinterpret_cast<const float4*>(g)[tid];
  float4 bv = reinterpret_cast<const float4*>(b)[tid];
  short4 o;
  o.x = f2bf((v.x - mu) * rstd * gv.x + bv.x);
  o.y = f2bf((v.y - mu) * rstd * gv.y + bv.y);
  o.z = f2bf((v.z - mu) * rstd * gv.z + bv.z);
  o.w = f2bf((v.w - mu) * rstd * gv.w + bv.w);
  reinterpret_cast<short4*>(out_ln + (size_t)row * D_)[tid] = o;
}

// ---------------- final residual + bias add: out = x + delta + bias ----------
__global__ __launch_bounds__(256) void addbias(const float* __restrict__ x,
                                               const short* __restrict__ delta,
                                               const float* __restrict__ bias,
                                               float* __restrict__ out) {
  const int i = blockIdx.x * 256 + threadIdx.x;
  float4 v = ((const float4*)x)[i];
  short4 dv = ((const short4*)delta)[i];
  const int col = (i * 4) & (D_ - 1);
  float4 pb = *(const float4*)(bias + col);
  v.x += bf2f(dv.x) + pb.x;
  v.y += bf2f(dv.y) + pb.y;
  v.z += bf2f(dv.z) + pb.z;
  v.w += bf2f(dv.w) + pb.w;
  ((float4*)out)[i] = v;
}

// ---------------- GEMM 128x128, BK=64, XOR-swizzled LDS, 2-phase dbuf --------
// MODE 0: store bf16.  MODE 2: bf16 out = gelu(acc + bias) (tanh-sigmoid).
template <int MODE>
__global__ __launch_bounds__(256) void gemm_bt(const short* __restrict__ A,
                                               const short* __restrict__ Bt,
                                               const float* __restrict__ bias,
                                               void* __restrict__ Cout,
                                               int M, int N, int K) {
  __shared__ short As[2][128 * 64];
  __shared__ short Bs[2][128 * 64];
  const int tid = threadIdx.x;
  const int gx = gridDim.x;
  const int nwg = gx * gridDim.y;
  int lin = blockIdx.y * gx + blockIdx.x;
  lin = (lin & 7) * (nwg >> 3) + (lin >> 3);
  const int m0 = (lin / gx) * 128, n0 = (lin % gx) * 128;
  const int wave = tid >> 6, lane = tid & 63;
  const int wm = (wave >> 1) * 64, wn = (wave & 1) * 64;
  const int lr = lane & 15, lg = lane >> 4;
  const int lx = lr & 7;

  f32x4 acc[4][4];
#pragma unroll
  for (int i = 0; i < 4; ++i)
#pragma unroll
    for (int j = 0; j < 4; ++j) acc[i][j] = f32x4{0.f, 0.f, 0.f, 0.f};

  const int sr = tid >> 3;
  const int scs = ((tid & 7) ^ (sr & 7)) * 8;
  const size_t arow = (size_t)(m0 + sr) * K + scs;
  const size_t brow = (size_t)(n0 + sr) * K + scs;

  auto stage = [&](int buf, int k0) {
#pragma unroll
    for (int p = 0; p < 4; ++p) {
      gload16(A + arow + (size_t)(p * 32) * K + k0, &As[buf][p * 2048 + tid * 8]);
      gload16(Bt + brow + (size_t)(p * 32) * K + k0, &Bs[buf][p * 2048 + tid * 8]);
    }
  };

  stage(0, 0);
  __syncthreads();
  int cur = 0;
  for (int k0 = 0; k0 < K; k0 += 64) {
    if (k0 + 64 < K) stage(cur ^ 1, k0 + 64);
    const short* Ab = &As[cur][0];
    const short* Bb = &Bs[cur][0];
#pragma unroll
    for (int kk = 0; kk < 2; ++kk) {
      bf16x8 af[4], bfr[4];
#pragma unroll
      for (int mi = 0; mi < 4; ++mi)
        af[mi] = *(const bf16x8*)(Ab + (wm + mi * 16 + lr) * 64 +
                                  (((kk * 4 + lg) ^ lx) * 8));
#pragma unroll
      for (int ni = 0; ni < 4; ++ni)
        bfr[ni] = *(const bf16x8*)(Bb + (wn + ni * 16 + lr) * 64 +
                                   (((kk * 4 + lg) ^ lx) * 8));
#pragma unroll
      for (int mi = 0; mi < 4; ++mi)
#pragma unroll
        for (int ni = 0; ni < 4; ++ni)
          acc[mi][ni] = __builtin_amdgcn_mfma_f32_16x16x32_bf16(
              af[mi], bfr[ni], acc[mi][ni], 0, 0, 0);
    }
    __syncthreads();
    cur ^= 1;
  }

#pragma unroll
  for (int mi = 0; mi < 4; ++mi) {
    const int row = m0 + wm + mi * 16 + lg * 4;
#pragma unroll
    for (int ni = 0; ni < 4; ++ni) {
      const int col = n0 + wn + ni * 16 + lr;
#pragma unroll
      for (int r = 0; r < 4; ++r) {
        const size_t idx = (size_t)(row + r) * N + col;
        const float v = acc[mi][ni][r];
        if (MODE == 0) {
          ((short*)Cout)[idx] = f2bf(v);
        } else {
          const float tt = v + bias[col];
          const float yy = fmaf(tt * tt * tt, 0.044715f, tt);
          const float e = EXP2(yy * -2.3022343813918633f);
          ((short*)Cout)[idx] = f2bf(tt / (1.0f + e));
        }
      }
    }
  }
}

// ---------------- batched-3 GEMM 128x128, BK=64 swizzled (cross-attn q/k/v) --
__global__ __launch_bounds__(256) void gemm_bt3(const short* __restrict__ A0,
                                                const short* __restrict__ A1,
                                                const short* __restrict__ A2,
                                                const short* __restrict__ B0,
                                                const short* __restrict__ B1,
                                                const short* __restrict__ B2,
                                                short* __restrict__ C0,
                                                short* __restrict__ C1,
                                                short* __restrict__ C2,
                                                int M, int N, int K) {
  const int z = blockIdx.z;
  const short* A  = z == 0 ? A0 : (z == 1 ? A1 : A2);
  const short* Bt = z == 0 ? B0 : (z == 1 ? B1 : B2);
  short* C        = z == 0 ? C0 : (z == 1 ? C1 : C2);

  __shared__ short As[2][128 * 64];
  __shared__ short Bs[2][128 * 64];
  const int tid = threadIdx.x;
  const int gx = gridDim.x;
  const int nwg = gx * gridDim.y;
  int lin = blockIdx.y * gx + blockIdx.x;
  lin = (lin & 7) * (nwg >> 3) + (lin >> 3);
  const int m0 = (lin / gx) * 128, n0 = (lin % gx) * 128;
  const int wave = tid >> 6, lane = tid & 63;
  const int wm = (wave >> 1) * 64, wn = (wave & 1) * 64;
  const int lr = lane & 15, lg = lane >> 4;
  const int lx = lr & 7;

  f32x4 acc[4][4];
#pragma unroll
  for (int i = 0; i < 4; ++i)
#pragma unroll
    for (int j = 0; j < 4; ++j) acc[i][j] = f32x4{0.f, 0.f, 0.f, 0.f};

  const int sr = tid >> 3;
  const int scs = ((tid & 7) ^ (sr & 7)) * 8;
  const size_t arow = (size_t)(m0 + sr) * K + scs;
  const size_t brow = (size_t)(n0 + sr) * K + scs;

  auto stage = [&](int buf, int k0) {
#pragma unroll
    for (int p = 0; p < 4; ++p) {
      gload16(A + arow + (size_t)(p * 32) * K + k0, &As[buf][p * 2048 + tid * 8]);
      gload16(Bt + brow + (size_t)(p * 32) * K + k0, &Bs[buf][p * 2048 + tid * 8]);
    }
  };

  stage(0, 0);
  __syncthreads();
  int cur = 0;
  for (int k0 = 0; k0 < K; k0 += 64) {
    if (k0 + 64 < K) stage(cur ^ 1, k0 + 64);
    const short* Ab = &As[cur][0];
    const short* Bb = &Bs[cur][0];
#pragma unroll
    for (int kk = 0; kk < 2; ++kk) {
      bf16x8 af[4], bfr[4];
#pragma unroll
      for (int mi = 0; mi < 4; ++mi)
        af[mi] = *(const bf16x8*)(Ab + (wm + mi * 16 + lr) * 64 +
                                  (((kk * 4 + lg) ^ lx) * 8));
#pragma unroll
      for (int ni = 0; ni < 4; ++ni)
        bfr[ni] = *(const bf16x8*)(Bb + (wn + ni * 16 + lr) * 64 +
                                   (((kk * 4 + lg) ^ lx) * 8));
#pragma unroll
      for (int mi = 0; mi < 4; ++mi)
#pragma unroll
        for (int ni = 0; ni < 4; ++ni)
          acc[mi][ni] = __builtin_amdgcn_mfma_f32_16x16x32_bf16(
              af[mi], bfr[ni], acc[mi][ni], 0, 0, 0);
    }
    __syncthreads();
    cur ^= 1;
  }

#pragma unroll
  for (int mi = 0; mi < 4; ++mi) {
    const int row = m0 + wm + mi * 16 + lg * 4;
#pragma unroll
    for (int ni = 0; ni < 4; ++ni) {
      const int col = n0 + wn + ni * 16 + lr;
#pragma unroll
      for (int r = 0; r < 4; ++r)
        C[(size_t)(row + r) * N + col] = f2bf(acc[mi][ni][r]);
    }
  }
}

// ---------------- per-head V transpose (bf16): (N x HD) -> (HD x N) ----------
__global__ __launch_bounds__(256) void vtrans(const short* __restrict__ in,
                                              short* __restrict__ out,
                                              int ldi, int N) {
  const int bh = blockIdx.z;
  const int b = bh >> 4, h = bh & 15;
  const short* ib = in + (size_t)b * N * ldi + h * HD_;
  short* ob = out + (size_t)bh * HD_ * N;
  __shared__ short t[32][33];
  const int tx = threadIdx.x, ty = threadIdx.y;
  const int n0 = blockIdx.x * 32, d0 = blockIdx.y * 32;
#pragma unroll
  for (int i = 0; i < 4; ++i)
    t[ty + i * 8][tx] = ib[(size_t)(n0 + ty + i * 8) * ldi + d0 + tx];
  __syncthreads();
#pragma unroll
  for (int i = 0; i < 4; ++i)
    ob[(size_t)(d0 + ty + i * 8) * N + n0 + tx] = t[tx][ty + i * 8];
}

// ---------------- flash attention: 128 q-rows/block (8 waves), KBLK=64 -------
// r11-proven structure (best measured): swapped QK^T per-wave body, 2-phase
// dbuf staging, causal qb remap + wave-skip, defer-max, ones-MFMA row-sum.
__global__ __launch_bounds__(512) void flash(const short* __restrict__ Q,
                                             const short* __restrict__ Kp,
                                             const short* __restrict__ Vt,
                                             short* __restrict__ O,
                                             int ldq, int ldk, int ldo,
                                             int NK, int causal) {
  const int bh = blockIdx.x;
  int qb = blockIdx.y;
  if (causal) qb = (qb < 8) ? (2 * qb) : (31 - 2 * qb);
  const int b = bh >> 4, h = bh & 15;
  const int q0 = qb * 128;
  const int tid = threadIdx.x, wave = tid >> 6, lane = tid & 63;
  const int lr = lane & 15, lg = lane >> 4;
  const int lx = lr & 7;

  const short* Qb = Q + (size_t)b * ND_ * ldq + h * HD_;
  const short* Kb = Kp + (size_t)b * NK * ldk + h * HD_;
  const short* Vb = Vt + (size_t)bh * HD_ * NK;
  short* Ob = O + (size_t)b * ND_ * ldo + h * HD_;

  __shared__ short Ks[2][64 * 64];
  __shared__ short Vs[2][64 * 64];
  __shared__ short Ps[8][16 * 64];

  const int qrow = q0 + wave * 16 + lr;
  const bf16x8 qf0 = *(const bf16x8*)(Qb + (size_t)qrow * ldq + lg * 8);
  const bf16x8 qf1 = *(const bf16x8*)(Qb + (size_t)qrow * ldq + 32 + lg * 8);

  const bf16x8 ONES = {0x3F80, 0x3F80, 0x3F80, 0x3F80,
                       0x3F80, 0x3F80, 0x3F80, 0x3F80};

  f32x4 oacc[4];
  f32x4 lacc = f32x4{0.f, 0.f, 0.f, 0.f};
  float m_own = -1e30f;
#pragma unroll
  for (int i = 0; i < 4; ++i) oacc[i] = f32x4{0.f, 0.f, 0.f, 0.f};

  const int sr0 = tid >> 3;
  const int ssw = ((tid & 7) ^ (sr0 & 7)) * 8;
  const int e0 = tid * 8;

  const float SC = 0.18033688011112042f;  // 1/sqrt(64) * log2(e)

  short* Pw = &Ps[wave][0];
  const int pbase = lr * 64 + (lg & 1) * 4;

  auto stage = [&](int buf, int k0) {
    gload16(Kb + (size_t)(k0 + sr0) * ldk + ssw, &Ks[buf][0] + e0);
    gload16(Vb + (size_t)sr0 * NK + k0 + ssw, &Vs[buf][0] + e0);
  };

  const int nkt = causal ? (2 * qb + 2) : (NK / 64);
  stage(0, 0);
  __syncthreads();
  int cur = 0;
  for (int t = 0; t < nkt; ++t) {
    const int k0 = t * 64;
    if (t + 1 < nkt) stage(cur ^ 1, k0 + 64);
    if (!causal || k0 <= q0 + wave * 16 + 15) {
      const short* Ksb = &Ks[cur][0];
      const short* Vsb = &Vs[cur][0];

      f32x4 st[4];
#pragma unroll
      for (int kb = 0; kb < 4; ++kb) {
        const bf16x8 kf0 = *(const bf16x8*)(Ksb + (kb * 16 + lr) * 64 + ((lg ^ lx) * 8));
        const bf16x8 kf1 = *(const bf16x8*)(Ksb + (kb * 16 + lr) * 64 + (((4 + lg) ^ lx) * 8));
        st[kb] = f32x4{0.f, 0.f, 0.f, 0.f};
        st[kb] = __builtin_amdgcn_mfma_f32_16x16x32_bf16(kf0, qf0, st[kb], 0, 0, 0);
        st[kb] = __builtin_amdgcn_mfma_f32_16x16x32_bf16(kf1, qf1, st[kb], 0, 0, 0);
      }
      if (causal && k0 + 63 > q0 + wave * 16) {
#pragma unroll
        for (int kb = 0; kb < 4; ++kb)
#pragma unroll
          for (int r = 0; r < 4; ++r)
            if ((k0 + kb * 16 + lg * 4 + r) > qrow) st[kb][r] = -3.0e38f;
      }

      float rm = st[0][0];
#pragma unroll
      for (int kb = 0; kb < 4; ++kb)
#pragma unroll
        for (int r = 0; r < 4; ++r)
          if (kb || r) rm = fmaxf(rm, st[kb][r]);
      rm = fmaxf(rm, __shfl_xor(rm, 16));
      rm = fmaxf(rm, __shfl_xor(rm, 32));

      if (!__all(rm - m_own <= 44.f)) {
        const float nm = fmaxf(m_own, rm);
        const float fac = EXP2((m_own - nm) * SC);
        m_own = nm;
        const float fr0 = __shfl(fac, (lg << 2) + 0);
        const float fr1 = __shfl(fac, (lg << 2) + 1);
        const float fr2 = __shfl(fac, (lg << 2) + 2);
        const float fr3 = __shfl(fac, (lg << 2) + 3);
#pragma unroll
        for (int db = 0; db < 4; ++db) {
          oacc[db][0] *= fr0; oacc[db][1] *= fr1;
          oacc[db][2] *= fr2; oacc[db][3] *= fr3;
        }
        lacc[0] *= fr0; lacc[1] *= fr1; lacc[2] *= fr2; lacc[3] *= fr3;
      }
      const float nmsc = m_own * SC;
#pragma unroll
      for (int kb = 0; kb < 4; ++kb)
#pragma unroll
        for (int r = 0; r < 4; ++r)
          st[kb][r] = EXP2(fmaf(st[kb][r], SC, -nmsc));

#pragma unroll
      for (int kb = 0; kb < 4; ++kb) {
        union { unsigned u[2]; unsigned long long ull; } pk;
        asm("v_cvt_pk_bf16_f32 %0, %1, %2"
            : "=v"(pk.u[0]) : "v"(st[kb][0]), "v"(st[kb][1]));
        asm("v_cvt_pk_bf16_f32 %0, %1, %2"
            : "=v"(pk.u[1]) : "v"(st[kb][2]), "v"(st[kb][3]));
        const int cs = kb * 2 + (lg >> 1);
        *(unsigned long long*)(Pw + pbase + ((cs ^ lx) * 8)) = pk.ull;
      }
      const bf16x8 pf0 = *(const bf16x8*)(Pw + lr * 64 + ((lg ^ lx) * 8));
      const bf16x8 pf1 = *(const bf16x8*)(Pw + lr * 64 + (((4 + lg) ^ lx) * 8));

#pragma unroll
      for (int db = 0; db < 4; ++db) {
        const bf16x8 vf0 = *(const bf16x8*)(Vsb + (db * 16 + lr) * 64 + ((lg ^ lx) * 8));
        const bf16x8 vf1 = *(const bf16x8*)(Vsb + (db * 16 + lr) * 64 + (((4 + lg) ^ lx) * 8));
        oacc[db] = __builtin_amdgcn_mfma_f32_16x16x32_bf16(pf0, vf0, oacc[db], 0, 0, 0);
        oacc[db] = __builtin_amdgcn_mfma_f32_16x16x32_bf16(pf1, vf1, oacc[db], 0, 0, 0);
      }
      lacc = __builtin_amdgcn_mfma_f32_16x16x32_bf16(pf0, ONES, lacc, 0, 0, 0);
      lacc = __builtin_amdgcn_mfma_f32_16x16x32_bf16(pf1, ONES, lacc, 0, 0, 0);
    }
    __syncthreads();
    cur ^= 1;
  }
#pragma unroll
  for (int db = 0; db < 4; ++db)
#pragma unroll
    for (int r = 0; r < 4; ++r) {
      const int q = q0 + wave * 16 + lg * 4 + r;
      Ob[(size_t)q * ldo + db * 16 + lr] = f2bf(oacc[db][r] / lacc[r]);
    }
}

// ---------------------------------------------------------------------------
extern "C" void kernel_launch(void* const* d_in, const int* in_sizes, int n_in,
                              void* d_out, int out_size, void* d_ws, size_t ws_size,
                              hipStream_t stream) {
  const float* x      = (const float*)d_in[0];
  const float* memory = (const float*)d_in[1];
  const float* ln1_g  = (const float*)d_in[2];
  const float* ln1_b  = (const float*)d_in[3];
  const float* Wqkv   = (const float*)d_in[4];
  const float* Wo_sa  = (const float*)d_in[5];
  const float* bo_sa  = (const float*)d_in[6];
  const float* ln2_g  = (const float*)d_in[7];
  const float* ln2_b  = (const float*)d_in[8];
  const float* Wq     = (const float*)d_in[9];
  const float* Wk     = (const float*)d_in[10];
  const float* Wv     = (const float*)d_in[11];
  const float* Wo_ca  = (const float*)d_in[12];
  const float* bo_ca  = (const float*)d_in[13];
  const float* ln3_g  = (const float*)d_in[14];
  const float* ln3_b  = (const float*)d_in[15];
  const float* W1     = (const float*)d_in[16];
  const float* b1     = (const float*)d_in[17];
  const float* W2     = (const float*)d_in[18];
  const float* b2     = (const float*)d_in[19];

  char* ws = (char*)d_ws;
  size_t o = 0;
  auto alloc = [&](size_t bytes) { char* p = ws + o; o += bytes; return p; };
  short* wqkv_t = (short*)alloc((size_t)3072 * 1024 * 2);
  short* wosa_t = (short*)alloc((size_t)1024 * 1024 * 2);
  short* wq_t   = (short*)alloc((size_t)1024 * 1024 * 2);
  short* wk_t   = (short*)alloc((size_t)1024 * 1024 * 2);
  short* wv_t   = (short*)alloc((size_t)1024 * 1024 * 2);
  short* woca_t = (short*)alloc((size_t)1024 * 1024 * 2);
  short* w1_t   = (short*)alloc((size_t)4096 * 1024 * 2);
  short* w2_t   = (short*)alloc((size_t)1024 * 4096 * 2);
  short* hbf    = (short*)alloc((size_t)T_ * 1024 * 2);  // ln-out AND delta buf
  short* bufa   = (short*)alloc((size_t)T_ * 3072 * 2);
  short* vt     = (short*)alloc((size_t)32 * 64 * 2048 * 2);
  short* attn   = (short*)alloc((size_t)T_ * 1024 * 2);
  short* membf  = (short*)alloc((size_t)T_ * 1024 * 2);
  float* x1     = (float*)alloc((size_t)T_ * 1024 * 4);
  float* x2     = (float*)alloc((size_t)T_ * 1024 * 4);
  if (o > ws_size) return;

  short* ffn = bufa;  // spans bufa(24MB)+vt(8MB), both dead by then
  short* qca = bufa;
  short* kca = bufa + (size_t)T_ * 1024;
  short* vca = bufa + (size_t)2 * T_ * 1024;

  const dim3 tb(32, 8);

  // merged weight prep (all transposes + memory cast) — one launch
  prep<<<dim3(20480), 256, 0, stream>>>(Wqkv, wqkv_t, W1, w1_t, W2, w2_t,
                                        Wo_sa, Wq, Wk, Wv, Wo_ca,
                                        wosa_t, wq_t, wk_t, wv_t, woca_t,
                                        memory, membf);

  // --- self-attention block ---
  ln_kernel<<<dim3(T_), 256, 0, stream>>>(x, ln1_g, ln1_b, hbf);
  gemm_bt<0><<<dim3(3072 / 128, T_ / 128), 256, 0, stream>>>(
      hbf, wqkv_t, nullptr, bufa, T_, 3072, 1024);
  vtrans<<<dim3(ND_ / 32, HD_ / 32, 32), tb, 0, stream>>>(bufa + 2048, vt, 3072, ND_);
  flash<<<dim3(32, ND_ / 128), 512, 0, stream>>>(
      bufa, bufa + 1024, vt, attn, 3072, 3072, 1024, ND_, 1);
  gemm_bt<0><<<dim3(1024 / 128, T_ / 128), 256, 0, stream>>>(
      attn, wosa_t, nullptr, hbf, T_, 1024, 1024);              // delta_sa -> hbf
  ln_fused<<<dim3(T_), 256, 0, stream>>>(x, hbf, bo_sa, ln2_g, ln2_b, hbf, x1);

  // --- cross-attention block ---
  gemm_bt3<<<dim3(1024 / 128, T_ / 128, 3), 256, 0, stream>>>(
      hbf, membf, membf, wq_t, wk_t, wv_t, qca, kca, vca, T_, 1024, 1024);
  vtrans<<<dim3(NE_ / 32, HD_ / 32, 32), tb, 0, stream>>>(vca, vt, 1024, NE_);
  flash<<<dim3(32, ND_ / 128), 512, 0, stream>>>(
      qca, kca, vt, attn, 1024, 1024, 1024, NE_, 0);
  gemm_bt<0><<<dim3(1024 / 128, T_ / 128), 256, 0, stream>>>(
      attn, woca_t, nullptr, hbf, T_, 1024, 1024);              // delta_ca -> hbf
  ln_fused<<<dim3(T_), 256, 0, stream>>>(x1, hbf, bo_ca, ln3_g, ln3_b, hbf, x2);

  // --- FFN block ---
  gemm_bt<2><<<dim3(4096 / 128, T_ / 128), 256, 0, stream>>>(
      hbf, w1_t, b1, ffn, T_, 4096, 1024);
  gemm_bt<0><<<dim3(1024 / 128, T_ / 128), 256, 0, stream>>>(
      ffn, w2_t, nullptr, hbf, T_, 1024, 4096);                 // delta_ffn -> hbf
  addbias<<<dim3((T_ * 1024) / (256 * 4)), 256, 0, stream>>>(
      x2, hbf, b2, (float*)d_out);
}

// Round 19
// 367.244 us; speedup vs baseline: 1.0466x; 1.0466x over previous
//
#include <hip/hip_runtime.h>
#include <hip/hip_bf16.h>
#include <math.h>

#define B_   2
#define ND_  2048
#define NE_  2048
#define D_   1024
#define H_   16
#define HD_  64
#define DFF_ 4096
#define T_   4096   // B_*ND_ tokens

typedef __attribute__((ext_vector_type(8))) short bf16x8;
typedef __attribute__((ext_vector_type(4))) float f32x4;

#if __has_builtin(__builtin_amdgcn_exp2f)
#define EXP2(x) __builtin_amdgcn_exp2f(x)
#else
#define EXP2(x) exp2f(x)
#endif

__device__ __forceinline__ short f2bf(float f) {
  union { float f; unsigned u; } v; v.f = f;
  return (short)((v.u + 0x7FFFu + ((v.u >> 16) & 1u)) >> 16);
}
__device__ __forceinline__ float bf2f(short s) {
  union { unsigned u; float f; } v; v.u = ((unsigned)(unsigned short)s) << 16;
  return v.f;
}

typedef const __attribute__((address_space(1))) void gvoid_t;
typedef __attribute__((address_space(3))) void lvoid_t;

__device__ __forceinline__ void gload16(const void* src, void* dst) {
  __builtin_amdgcn_global_load_lds((gvoid_t*)src, (lvoid_t*)dst, 16, 0, 0);
}

// ---------------- merged weight-prep: all transposes + memory cast -----------
__global__ __launch_bounds__(256) void prep(
    const float* __restrict__ Wqkv, short* __restrict__ wqkv_t,
    const float* __restrict__ W1, short* __restrict__ w1_t,
    const float* __restrict__ W2, short* __restrict__ w2_t,
    const float* __restrict__ i0, const float* __restrict__ i1,
    const float* __restrict__ i2, const float* __restrict__ i3,
    const float* __restrict__ i4,
    short* __restrict__ o0, short* __restrict__ o1, short* __restrict__ o2,
    short* __restrict__ o3, short* __restrict__ o4,
    const float* __restrict__ mem, short* __restrict__ membf) {
  const int id = blockIdx.x;
  const int tid = threadIdx.x;
  if (id >= 16384) {  // memory cast
    const int i = (id - 16384) * 256 + tid;
    float4 v = ((const float4*)mem)[i];
    short4 o;
    o.x = f2bf(v.x); o.y = f2bf(v.y); o.z = f2bf(v.z); o.w = f2bf(v.w);
    ((short4*)membf)[i] = o;
    return;
  }
  const float* in; short* out; int K, N, bx, by;
  if (id < 3072) {
    in = Wqkv; out = wqkv_t; K = 1024; N = 3072; bx = id % 96; by = id / 96;
  } else if (id < 7168) {
    const int t = id - 3072;
    in = W1; out = w1_t; K = 1024; N = 4096; bx = t % 128; by = t / 128;
  } else if (id < 11264) {
    const int t = id - 7168;
    in = W2; out = w2_t; K = 4096; N = 1024; bx = t % 32; by = t / 32;
  } else {
    const int t = id - 11264;
    const int z = t >> 10, r = t & 1023;
    bx = r % 32; by = r / 32; K = 1024; N = 1024;
    in  = z == 0 ? i0 : z == 1 ? i1 : z == 2 ? i2 : z == 3 ? i3 : i4;
    out = z == 0 ? o0 : z == 1 ? o1 : z == 2 ? o2 : z == 3 ? o3 : o4;
  }
  __shared__ float tb[32][33];
  const int tx = tid & 31, ty = tid >> 5;
  const int n0 = bx * 32, k0 = by * 32;
#pragma unroll
  for (int i = 0; i < 4; ++i)
    tb[ty + i * 8][tx] = in[(size_t)(k0 + ty + i * 8) * N + n0 + tx];
  __syncthreads();
#pragma unroll
  for (int i = 0; i < 4; ++i)
    out[(size_t)(n0 + ty + i * 8) * K + k0 + tx] = f2bf(tb[tx][ty + i * 8]);
}

// ---------------- LayerNorm (row of 1024) fp32 -> bf16 -----------------------
__global__ __launch_bounds__(256) void ln_kernel(const float* __restrict__ x,
                                                 const float* __restrict__ g,
                                                 const float* __restrict__ b,
                                                 short* __restrict__ out) {
  const int row = blockIdx.x;
  const int tid = threadIdx.x;
  const float* xr = x + (size_t)row * D_;
  float4 v = reinterpret_cast<const float4*>(xr)[tid];
  float s  = v.x + v.y + v.z + v.w;
  float s2 = v.x * v.x + v.y * v.y + v.z * v.z + v.w * v.w;
#pragma unroll
  for (int m = 1; m < 64; m <<= 1) {
    s  += __shfl_xor(s, m);
    s2 += __shfl_xor(s2, m);
  }
  __shared__ float ss[4], ss2[4];
  const int w = tid >> 6;
  if ((tid & 63) == 0) { ss[w] = s; ss2[w] = s2; }
  __syncthreads();
  s  = ss[0] + ss[1] + ss[2] + ss[3];
  s2 = ss2[0] + ss2[1] + ss2[2] + ss2[3];
  const float mu   = s * (1.0f / D_);
  const float var  = s2 * (1.0f / D_) - mu * mu;
  const float rstd = rsqrtf(var + 1e-5f);
  float4 gv = reinterpret_cast<const float4*>(g)[tid];
  float4 bv = reinterpret_cast<const float4*>(b)[tid];
  short4 o;
  o.x = f2bf((v.x - mu) * rstd * gv.x + bv.x);
  o.y = f2bf((v.y - mu) * rstd * gv.y + bv.y);
  o.z = f2bf((v.z - mu) * rstd * gv.z + bv.z);
  o.w = f2bf((v.w - mu) * rstd * gv.w + bv.w);
  reinterpret_cast<short4*>(out + (size_t)row * D_)[tid] = o;
}

// ---------------- fused residual + bias + LayerNorm --------------------------
__global__ __launch_bounds__(256) void ln_fused(const float* __restrict__ xprev,
                                                const short* delta,
                                                const float* __restrict__ pbias,
                                                const float* __restrict__ g,
                                                const float* __restrict__ b,
                                                short* out_ln,
                                                float* __restrict__ out_x) {
  const int row = blockIdx.x;
  const int tid = threadIdx.x;
  float4 v = reinterpret_cast<const float4*>(xprev + (size_t)row * D_)[tid];
  short4 dv = reinterpret_cast<const short4*>(delta + (size_t)row * D_)[tid];
  float4 pb = reinterpret_cast<const float4*>(pbias)[tid];
  v.x += bf2f(dv.x) + pb.x;
  v.y += bf2f(dv.y) + pb.y;
  v.z += bf2f(dv.z) + pb.z;
  v.w += bf2f(dv.w) + pb.w;
  float s  = v.x + v.y + v.z + v.w;
  float s2 = v.x * v.x + v.y * v.y + v.z * v.z + v.w * v.w;
#pragma unroll
  for (int m = 1; m < 64; m <<= 1) {
    s  += __shfl_xor(s, m);
    s2 += __shfl_xor(s2, m);
  }
  __shared__ float ss[4], ss2[4];
  const int w = tid >> 6;
  if ((tid & 63) == 0) { ss[w] = s; ss2[w] = s2; }
  __syncthreads();
  s  = ss[0] + ss[1] + ss[2] + ss[3];
  s2 = ss2[0] + ss2[1] + ss2[2] + ss2[3];
  const float mu   = s * (1.0f / D_);
  const float var  = s2 * (1.0f / D_) - mu * mu;
  const float rstd = rsqrtf(var + 1e-5f);
  reinterpret_cast<float4*>(out_x + (size_t)row * D_)[tid] = v;
  float4 gv = reinterpret_cast<const float4*>(g)[tid];
  float4 bv = reinterpret_cast<const float4*>(b)[tid];
  short4 o;
  o.x = f2bf((v.x - mu) * rstd * gv.x + bv.x);
  o.y = f2bf((v.y - mu) * rstd * gv.y + bv.y);
  o.z = f2bf((v.z - mu) * rstd * gv.z + bv.z);
  o.w = f2bf((v.w - mu) * rstd * gv.w + bv.w);
  reinterpret_cast<short4*>(out_ln + (size_t)row * D_)[tid] = o;
}

// ---------------- final residual + bias add: out = x + delta + bias ----------
__global__ __launch_bounds__(256) void addbias(const float* __restrict__ x,
                                               const short* __restrict__ delta,
                                               const float* __restrict__ bias,
                                               float* __restrict__ out) {
  const int i = blockIdx.x * 256 + threadIdx.x;
  float4 v = ((const float4*)x)[i];
  short4 dv = ((const short4*)delta)[i];
  const int col = (i * 4) & (D_ - 1);
  float4 pb = *(const float4*)(bias + col);
  v.x += bf2f(dv.x) + pb.x;
  v.y += bf2f(dv.y) + pb.y;
  v.z += bf2f(dv.z) + pb.z;
  v.w += bf2f(dv.w) + pb.w;
  ((float4*)out)[i] = v;
}

// ---------------- GEMM 128x128, BK=64, XOR-swizzled LDS, 2-phase dbuf --------
template <int MODE>
__global__ __launch_bounds__(256) void gemm_bt(const short* __restrict__ A,
                                               const short* __restrict__ Bt,
                                               const float* __restrict__ bias,
                                               void* __restrict__ Cout,
                                               int M, int N, int K) {
  __shared__ short As[2][128 * 64];
  __shared__ short Bs[2][128 * 64];
  const int tid = threadIdx.x;
  const int gx = gridDim.x;
  const int nwg = gx * gridDim.y;
  int lin = blockIdx.y * gx + blockIdx.x;
  lin = (lin & 7) * (nwg >> 3) + (lin >> 3);
  const int m0 = (lin / gx) * 128, n0 = (lin % gx) * 128;
  const int wave = tid >> 6, lane = tid & 63;
  const int wm = (wave >> 1) * 64, wn = (wave & 1) * 64;
  const int lr = lane & 15, lg = lane >> 4;
  const int lx = lr & 7;

  f32x4 acc[4][4];
#pragma unroll
  for (int i = 0; i < 4; ++i)
#pragma unroll
    for (int j = 0; j < 4; ++j) acc[i][j] = f32x4{0.f, 0.f, 0.f, 0.f};

  const int sr = tid >> 3;
  const int scs = ((tid & 7) ^ (sr & 7)) * 8;
  const size_t arow = (size_t)(m0 + sr) * K + scs;
  const size_t brow = (size_t)(n0 + sr) * K + scs;

  auto stage = [&](int buf, int k0) {
#pragma unroll
    for (int p = 0; p < 4; ++p) {
      gload16(A + arow + (size_t)(p * 32) * K + k0, &As[buf][p * 2048 + tid * 8]);
      gload16(Bt + brow + (size_t)(p * 32) * K + k0, &Bs[buf][p * 2048 + tid * 8]);
    }
  };

  stage(0, 0);
  __syncthreads();
  int cur = 0;
  for (int k0 = 0; k0 < K; k0 += 64) {
    if (k0 + 64 < K) stage(cur ^ 1, k0 + 64);
    const short* Ab = &As[cur][0];
    const short* Bb = &Bs[cur][0];
#pragma unroll
    for (int kk = 0; kk < 2; ++kk) {
      bf16x8 af[4], bfr[4];
#pragma unroll
      for (int mi = 0; mi < 4; ++mi)
        af[mi] = *(const bf16x8*)(Ab + (wm + mi * 16 + lr) * 64 +
                                  (((kk * 4 + lg) ^ lx) * 8));
#pragma unroll
      for (int ni = 0; ni < 4; ++ni)
        bfr[ni] = *(const bf16x8*)(Bb + (wn + ni * 16 + lr) * 64 +
                                   (((kk * 4 + lg) ^ lx) * 8));
#pragma unroll
      for (int mi = 0; mi < 4; ++mi)
#pragma unroll
        for (int ni = 0; ni < 4; ++ni)
          acc[mi][ni] = __builtin_amdgcn_mfma_f32_16x16x32_bf16(
              af[mi], bfr[ni], acc[mi][ni], 0, 0, 0);
    }
    __syncthreads();
    cur ^= 1;
  }

#pragma unroll
  for (int mi = 0; mi < 4; ++mi) {
    const int row = m0 + wm + mi * 16 + lg * 4;
#pragma unroll
    for (int ni = 0; ni < 4; ++ni) {
      const int col = n0 + wn + ni * 16 + lr;
#pragma unroll
      for (int r = 0; r < 4; ++r) {
        const size_t idx = (size_t)(row + r) * N + col;
        const float v = acc[mi][ni][r];
        if (MODE == 0) {
          ((short*)Cout)[idx] = f2bf(v);
        } else {
          const float tt = v + bias[col];
          const float yy = fmaf(tt * tt * tt, 0.044715f, tt);
          const float e = EXP2(yy * -2.3022343813918633f);
          ((short*)Cout)[idx] = f2bf(tt / (1.0f + e));
        }
      }
    }
  }
}

// ---------------- batched-3 GEMM 128x128, BK=64 swizzled (cross-attn q/k/v) --
__global__ __launch_bounds__(256) void gemm_bt3(const short* __restrict__ A0,
                                                const short* __restrict__ A1,
                                                const short* __restrict__ A2,
                                                const short* __restrict__ B0,
                                                const short* __restrict__ B1,
                                                const short* __restrict__ B2,
                                                short* __restrict__ C0,
                                                short* __restrict__ C1,
                                                short* __restrict__ C2,
                                                int M, int N, int K) {
  const int z = blockIdx.z;
  const short* A  = z == 0 ? A0 : (z == 1 ? A1 : A2);
  const short* Bt = z == 0 ? B0 : (z == 1 ? B1 : B2);
  short* C        = z == 0 ? C0 : (z == 1 ? C1 : C2);

  __shared__ short As[2][128 * 64];
  __shared__ short Bs[2][128 * 64];
  const int tid = threadIdx.x;
  const int gx = gridDim.x;
  const int nwg = gx * gridDim.y;
  int lin = blockIdx.y * gx + blockIdx.x;
  lin = (lin & 7) * (nwg >> 3) + (lin >> 3);
  const int m0 = (lin / gx) * 128, n0 = (lin % gx) * 128;
  const int wave = tid >> 6, lane = tid & 63;
  const int wm = (wave >> 1) * 64, wn = (wave & 1) * 64;
  const int lr = lane & 15, lg = lane >> 4;
  const int lx = lr & 7;

  f32x4 acc[4][4];
#pragma unroll
  for (int i = 0; i < 4; ++i)
#pragma unroll
    for (int j = 0; j < 4; ++j) acc[i][j] = f32x4{0.f, 0.f, 0.f, 0.f};

  const int sr = tid >> 3;
  const int scs = ((tid & 7) ^ (sr & 7)) * 8;
  const size_t arow = (size_t)(m0 + sr) * K + scs;
  const size_t brow = (size_t)(n0 + sr) * K + scs;

  auto stage = [&](int buf, int k0) {
#pragma unroll
    for (int p = 0; p < 4; ++p) {
      gload16(A + arow + (size_t)(p * 32) * K + k0, &As[buf][p * 2048 + tid * 8]);
      gload16(Bt + brow + (size_t)(p * 32) * K + k0, &Bs[buf][p * 2048 + tid * 8]);
    }
  };

  stage(0, 0);
  __syncthreads();
  int cur = 0;
  for (int k0 = 0; k0 < K; k0 += 64) {
    if (k0 + 64 < K) stage(cur ^ 1, k0 + 64);
    const short* Ab = &As[cur][0];
    const short* Bb = &Bs[cur][0];
#pragma unroll
    for (int kk = 0; kk < 2; ++kk) {
      bf16x8 af[4], bfr[4];
#pragma unroll
      for (int mi = 0; mi < 4; ++mi)
        af[mi] = *(const bf16x8*)(Ab + (wm + mi * 16 + lr) * 64 +
                                  (((kk * 4 + lg) ^ lx) * 8));
#pragma unroll
      for (int ni = 0; ni < 4; ++ni)
        bfr[ni] = *(const bf16x8*)(Bb + (wn + ni * 16 + lr) * 64 +
                                   (((kk * 4 + lg) ^ lx) * 8));
#pragma unroll
      for (int mi = 0; mi < 4; ++mi)
#pragma unroll
        for (int ni = 0; ni < 4; ++ni)
          acc[mi][ni] = __builtin_amdgcn_mfma_f32_16x16x32_bf16(
              af[mi], bfr[ni], acc[mi][ni], 0, 0, 0);
    }
    __syncthreads();
    cur ^= 1;
  }

#pragma unroll
  for (int mi = 0; mi < 4; ++mi) {
    const int row = m0 + wm + mi * 16 + lg * 4;
#pragma unroll
    for (int ni = 0; ni < 4; ++ni) {
      const int col = n0 + wn + ni * 16 + lr;
#pragma unroll
      for (int r = 0; r < 4; ++r)
        C[(size_t)(row + r) * N + col] = f2bf(acc[mi][ni][r]);
    }
  }
}

// ---------------- GEMM 64x128 tile, BK=64 swizzled, bf16 delta out -----------
__global__ __launch_bounds__(256) void gemm_bt64(const short* __restrict__ A,
                                                 const short* __restrict__ Bt,
                                                 short* __restrict__ Cout,
                                                 int M, int N, int K) {
  __shared__ short As[2][64 * 64];
  __shared__ short Bs[2][128 * 64];
  const int tid = threadIdx.x;
  const int gx = gridDim.x;
  const int nwg = gx * gridDim.y;
  int lin = blockIdx.y * gx + blockIdx.x;
  lin = (lin & 7) * (nwg >> 3) + (lin >> 3);
  const int m0 = (lin / gx) * 64, n0 = (lin % gx) * 128;
  const int wave = tid >> 6, lane = tid & 63;
  const int wn = wave * 32;
  const int lr = lane & 15, lg = lane >> 4;
  const int lx = lr & 7;

  f32x4 acc[4][2];
#pragma unroll
  for (int i = 0; i < 4; ++i)
#pragma unroll
    for (int j = 0; j < 2; ++j) acc[i][j] = f32x4{0.f, 0.f, 0.f, 0.f};

  const int sr = tid >> 3;
  const int scs = ((tid & 7) ^ (sr & 7)) * 8;
  const size_t arow = (size_t)(m0 + sr) * K + scs;
  const size_t brow = (size_t)(n0 + sr) * K + scs;

  auto stage = [&](int buf, int k0) {
#pragma unroll
    for (int p = 0; p < 2; ++p)
      gload16(A + arow + (size_t)(p * 32) * K + k0, &As[buf][p * 2048 + tid * 8]);
#pragma unroll
    for (int p = 0; p < 4; ++p)
      gload16(Bt + brow + (size_t)(p * 32) * K + k0, &Bs[buf][p * 2048 + tid * 8]);
  };

  stage(0, 0);
  __syncthreads();
  int cur = 0;
  for (int k0 = 0; k0 < K; k0 += 64) {
    if (k0 + 64 < K) stage(cur ^ 1, k0 + 64);
    const short* Ab = &As[cur][0];
    const short* Bb = &Bs[cur][0];
#pragma unroll
    for (int kk = 0; kk < 2; ++kk) {
      bf16x8 af[4], bfr[2];
#pragma unroll
      for (int mi = 0; mi < 4; ++mi)
        af[mi] = *(const bf16x8*)(Ab + (mi * 16 + lr) * 64 +
                                  (((kk * 4 + lg) ^ lx) * 8));
#pragma unroll
      for (int ni = 0; ni < 2; ++ni)
        bfr[ni] = *(const bf16x8*)(Bb + (wn + ni * 16 + lr) * 64 +
                                   (((kk * 4 + lg) ^ lx) * 8));
#pragma unroll
      for (int mi = 0; mi < 4; ++mi)
#pragma unroll
        for (int ni = 0; ni < 2; ++ni)
          acc[mi][ni] = __builtin_amdgcn_mfma_f32_16x16x32_bf16(
              af[mi], bfr[ni], acc[mi][ni], 0, 0, 0);
    }
    __syncthreads();
    cur ^= 1;
  }

#pragma unroll
  for (int mi = 0; mi < 4; ++mi) {
    const int row = m0 + mi * 16 + lg * 4;
#pragma unroll
    for (int ni = 0; ni < 2; ++ni) {
      const int col = n0 + wn + ni * 16 + lr;
#pragma unroll
      for (int r = 0; r < 4; ++r)
        Cout[(size_t)(row + r) * N + col] = f2bf(acc[mi][ni][r]);
    }
  }
}

// ---------------- per-head V transpose (bf16): (N x HD) -> (HD x N) ----------
__global__ __launch_bounds__(256) void vtrans(const short* __restrict__ in,
                                              short* __restrict__ out,
                                              int ldi, int N) {
  const int bh = blockIdx.z;
  const int b = bh >> 4, h = bh & 15;
  const short* ib = in + (size_t)b * N * ldi + h * HD_;
  short* ob = out + (size_t)bh * HD_ * N;
  __shared__ short t[32][33];
  const int tx = threadIdx.x, ty = threadIdx.y;
  const int n0 = blockIdx.x * 32, d0 = blockIdx.y * 32;
#pragma unroll
  for (int i = 0; i < 4; ++i)
    t[ty + i * 8][tx] = ib[(size_t)(n0 + ty + i * 8) * ldi + d0 + tx];
  __syncthreads();
#pragma unroll
  for (int i = 0; i < 4; ++i)
    ob[(size_t)(d0 + ty + i * 8) * N + n0 + tx] = t[tx][ty + i * 8];
}

// ---------------- flash attention: 128 q-rows/block (8 waves), KBLK=64 -------
// r11-proven structure (best measured): swapped QK^T per-wave body, 2-phase
// dbuf staging, causal qb remap + wave-skip, defer-max, ones-MFMA row-sum.
__global__ __launch_bounds__(512) void flash(const short* __restrict__ Q,
                                             const short* __restrict__ Kp,
                                             const short* __restrict__ Vt,
                                             short* __restrict__ O,
                                             int ldq, int ldk, int ldo,
                                             int NK, int causal) {
  const int bh = blockIdx.x;
  int qb = blockIdx.y;
  if (causal) qb = (qb < 8) ? (2 * qb) : (31 - 2 * qb);
  const int b = bh >> 4, h = bh & 15;
  const int q0 = qb * 128;
  const int tid = threadIdx.x, wave = tid >> 6, lane = tid & 63;
  const int lr = lane & 15, lg = lane >> 4;
  const int lx = lr & 7;

  const short* Qb = Q + (size_t)b * ND_ * ldq + h * HD_;
  const short* Kb = Kp + (size_t)b * NK * ldk + h * HD_;
  const short* Vb = Vt + (size_t)bh * HD_ * NK;
  short* Ob = O + (size_t)b * ND_ * ldo + h * HD_;

  __shared__ short Ks[2][64 * 64];
  __shared__ short Vs[2][64 * 64];
  __shared__ short Ps[8][16 * 64];

  const int qrow = q0 + wave * 16 + lr;
  const bf16x8 qf0 = *(const bf16x8*)(Qb + (size_t)qrow * ldq + lg * 8);
  const bf16x8 qf1 = *(const bf16x8*)(Qb + (size_t)qrow * ldq + 32 + lg * 8);

  const bf16x8 ONES = {0x3F80, 0x3F80, 0x3F80, 0x3F80,
                       0x3F80, 0x3F80, 0x3F80, 0x3F80};

  f32x4 oacc[4];
  f32x4 lacc = f32x4{0.f, 0.f, 0.f, 0.f};
  float m_own = -1e30f;
#pragma unroll
  for (int i = 0; i < 4; ++i) oacc[i] = f32x4{0.f, 0.f, 0.f, 0.f};

  const int sr0 = tid >> 3;
  const int ssw = ((tid & 7) ^ (sr0 & 7)) * 8;
  const int e0 = tid * 8;

  const float SC = 0.18033688011112042f;  // 1/sqrt(64) * log2(e)

  short* Pw = &Ps[wave][0];
  const int pbase = lr * 64 + (lg & 1) * 4;

  auto stage = [&](int buf, int k0) {
    gload16(Kb + (size_t)(k0 + sr0) * ldk + ssw, &Ks[buf][0] + e0);
    gload16(Vb + (size_t)sr0 * NK + k0 + ssw, &Vs[buf][0] + e0);
  };

  const int nkt = causal ? (2 * qb + 2) : (NK / 64);
  stage(0, 0);
  __syncthreads();
  int cur = 0;
  for (int t = 0; t < nkt; ++t) {
    const int k0 = t * 64;
    if (t + 1 < nkt) stage(cur ^ 1, k0 + 64);
    if (!causal || k0 <= q0 + wave * 16 + 15) {
      const short* Ksb = &Ks[cur][0];
      const short* Vsb = &Vs[cur][0];

      f32x4 st[4];
#pragma unroll
      for (int kb = 0; kb < 4; ++kb) {
        const bf16x8 kf0 = *(const bf16x8*)(Ksb + (kb * 16 + lr) * 64 + ((lg ^ lx) * 8));
        const bf16x8 kf1 = *(const bf16x8*)(Ksb + (kb * 16 + lr) * 64 + (((4 + lg) ^ lx) * 8));
        st[kb] = f32x4{0.f, 0.f, 0.f, 0.f};
        st[kb] = __builtin_amdgcn_mfma_f32_16x16x32_bf16(kf0, qf0, st[kb], 0, 0, 0);
        st[kb] = __builtin_amdgcn_mfma_f32_16x16x32_bf16(kf1, qf1, st[kb], 0, 0, 0);
      }
      if (causal && k0 + 63 > q0 + wave * 16) {
#pragma unroll
        for (int kb = 0; kb < 4; ++kb)
#pragma unroll
          for (int r = 0; r < 4; ++r)
            if ((k0 + kb * 16 + lg * 4 + r) > qrow) st[kb][r] = -3.0e38f;
      }

      float rm = st[0][0];
#pragma unroll
      for (int kb = 0; kb < 4; ++kb)
#pragma unroll
        for (int r = 0; r < 4; ++r)
          if (kb || r) rm = fmaxf(rm, st[kb][r]);
      rm = fmaxf(rm, __shfl_xor(rm, 16));
      rm = fmaxf(rm, __shfl_xor(rm, 32));

      if (!__all(rm - m_own <= 44.f)) {
        const float nm = fmaxf(m_own, rm);
        const float fac = EXP2((m_own - nm) * SC);
        m_own = nm;
        const float fr0 = __shfl(fac, (lg << 2) + 0);
        const float fr1 = __shfl(fac, (lg << 2) + 1);
        const float fr2 = __shfl(fac, (lg << 2) + 2);
        const float fr3 = __shfl(fac, (lg << 2) + 3);
#pragma unroll
        for (int db = 0; db < 4; ++db) {
          oacc[db][0] *= fr0; oacc[db][1] *= fr1;
          oacc[db][2] *= fr2; oacc[db][3] *= fr3;
        }
        lacc[0] *= fr0; lacc[1] *= fr1; lacc[2] *= fr2; lacc[3] *= fr3;
      }
      const float nmsc = m_own * SC;
#pragma unroll
      for (int kb = 0; kb < 4; ++kb)
#pragma unroll
        for (int r = 0; r < 4; ++r)
          st[kb][r] = EXP2(fmaf(st[kb][r], SC, -nmsc));

#pragma unroll
      for (int kb = 0; kb < 4; ++kb) {
        union { unsigned u[2]; unsigned long long ull; } pk;
        asm("v_cvt_pk_bf16_f32 %0, %1, %2"
            : "=v"(pk.u[0]) : "v"(st[kb][0]), "v"(st[kb][1]));
        asm("v_cvt_pk_bf16_f32 %0, %1, %2"
            : "=v"(pk.u[1]) : "v"(st[kb][2]), "v"(st[kb][3]));
        const int cs = kb * 2 + (lg >> 1);
        *(unsigned long long*)(Pw + pbase + ((cs ^ lx) * 8)) = pk.ull;
      }
      const bf16x8 pf0 = *(const bf16x8*)(Pw + lr * 64 + ((lg ^ lx) * 8));
      const bf16x8 pf1 = *(const bf16x8*)(Pw + lr * 64 + (((4 + lg) ^ lx) * 8));

#pragma unroll
      for (int db = 0; db < 4; ++db) {
        const bf16x8 vf0 = *(const bf16x8*)(Vsb + (db * 16 + lr) * 64 + ((lg ^ lx) * 8));
        const bf16x8 vf1 = *(const bf16x8*)(Vsb + (db * 16 + lr) * 64 + (((4 + lg) ^ lx) * 8));
        oacc[db] = __builtin_amdgcn_mfma_f32_16x16x32_bf16(pf0, vf0, oacc[db], 0, 0, 0);
        oacc[db] = __builtin_amdgcn_mfma_f32_16x16x32_bf16(pf1, vf1, oacc[db], 0, 0, 0);
      }
      lacc = __builtin_amdgcn_mfma_f32_16x16x32_bf16(pf0, ONES, lacc, 0, 0, 0);
      lacc = __builtin_amdgcn_mfma_f32_16x16x32_bf16(pf1, ONES, lacc, 0, 0, 0);
    }
    __syncthreads();
    cur ^= 1;
  }
#pragma unroll
  for (int db = 0; db < 4; ++db)
#pragma unroll
    for (int r = 0; r < 4; ++r) {
      const int q = q0 + wave * 16 + lg * 4 + r;
      Ob[(size_t)q * ldo + db * 16 + lr] = f2bf(oacc[db][r] / lacc[r]);
    }
}

// ---------------------------------------------------------------------------
extern "C" void kernel_launch(void* const* d_in, const int* in_sizes, int n_in,
                              void* d_out, int out_size, void* d_ws, size_t ws_size,
                              hipStream_t stream) {
  const float* x      = (const float*)d_in[0];
  const float* memory = (const float*)d_in[1];
  const float* ln1_g  = (const float*)d_in[2];
  const float* ln1_b  = (const float*)d_in[3];
  const float* Wqkv   = (const float*)d_in[4];
  const float* Wo_sa  = (const float*)d_in[5];
  const float* bo_sa  = (const float*)d_in[6];
  const float* ln2_g  = (const float*)d_in[7];
  const float* ln2_b  = (const float*)d_in[8];
  const float* Wq     = (const float*)d_in[9];
  const float* Wk     = (const float*)d_in[10];
  const float* Wv     = (const float*)d_in[11];
  const float* Wo_ca  = (const float*)d_in[12];
  const float* bo_ca  = (const float*)d_in[13];
  const float* ln3_g  = (const float*)d_in[14];
  const float* ln3_b  = (const float*)d_in[15];
  const float* W1     = (const float*)d_in[16];
  const float* b1     = (const float*)d_in[17];
  const float* W2     = (const float*)d_in[18];
  const float* b2     = (const float*)d_in[19];

  char* ws = (char*)d_ws;
  size_t o = 0;
  auto alloc = [&](size_t bytes) { char* p = ws + o; o += bytes; return p; };
  short* wqkv_t = (short*)alloc((size_t)3072 * 1024 * 2);
  short* wosa_t = (short*)alloc((size_t)1024 * 1024 * 2);
  short* wq_t   = (short*)alloc((size_t)1024 * 1024 * 2);
  short* wk_t   = (short*)alloc((size_t)1024 * 1024 * 2);
  short* wv_t   = (short*)alloc((size_t)1024 * 1024 * 2);
  short* woca_t = (short*)alloc((size_t)1024 * 1024 * 2);
  short* w1_t   = (short*)alloc((size_t)4096 * 1024 * 2);
  short* w2_t   = (short*)alloc((size_t)1024 * 4096 * 2);
  short* hbf    = (short*)alloc((size_t)T_ * 1024 * 2);  // ln-out AND delta buf
  short* bufa   = (short*)alloc((size_t)T_ * 3072 * 2);
  short* vt     = (short*)alloc((size_t)32 * 64 * 2048 * 2);
  short* attn   = (short*)alloc((size_t)T_ * 1024 * 2);
  short* membf  = (short*)alloc((size_t)T_ * 1024 * 2);
  float* x1     = (float*)alloc((size_t)T_ * 1024 * 4);
  float* x2     = (float*)alloc((size_t)T_ * 1024 * 4);
  if (o > ws_size) return;

  short* ffn = bufa;  // spans bufa(24MB)+vt(8MB), both dead by then
  short* qca = bufa;
  short* kca = bufa + (size_t)T_ * 1024;
  short* vca = bufa + (size_t)2 * T_ * 1024;

  const dim3 tb(32, 8);

  // merged weight prep (all transposes + memory cast) — one launch
  prep<<<dim3(20480), 256, 0, stream>>>(Wqkv, wqkv_t, W1, w1_t, W2, w2_t,
                                        Wo_sa, Wq, Wk, Wv, Wo_ca,
                                        wosa_t, wq_t, wk_t, wv_t, woca_t,
                                        memory, membf);

  // --- self-attention block ---
  ln_kernel<<<dim3(T_), 256, 0, stream>>>(x, ln1_g, ln1_b, hbf);
  gemm_bt<0><<<dim3(3072 / 128, T_ / 128), 256, 0, stream>>>(
      hbf, wqkv_t, nullptr, bufa, T_, 3072, 1024);
  vtrans<<<dim3(ND_ / 32, HD_ / 32, 32), tb, 0, stream>>>(bufa + 2048, vt, 3072, ND_);
  flash<<<dim3(32, ND_ / 128), 512, 0, stream>>>(
      bufa, bufa + 1024, vt, attn, 3072, 3072, 1024, ND_, 1);
  gemm_bt64<<<dim3(1024 / 128, T_ / 64), 256, 0, stream>>>(
      attn, wosa_t, hbf, T_, 1024, 1024);                       // delta_sa -> hbf
  ln_fused<<<dim3(T_), 256, 0, stream>>>(x, hbf, bo_sa, ln2_g, ln2_b, hbf, x1);

  // --- cross-attention block ---
  gemm_bt3<<<dim3(1024 / 128, T_ / 128, 3), 256, 0, stream>>>(
      hbf, membf, membf, wq_t, wk_t, wv_t, qca, kca, vca, T_, 1024, 1024);
  vtrans<<<dim3(NE_ / 32, HD_ / 32, 32), tb, 0, stream>>>(vca, vt, 1024, NE_);
  flash<<<dim3(32, ND_ / 128), 512, 0, stream>>>(
      qca, kca, vt, attn, 1024, 1024, 1024, NE_, 0);
  gemm_bt64<<<dim3(1024 / 128, T_ / 64), 256, 0, stream>>>(
      attn, woca_t, hbf, T_, 1024, 1024);                       // delta_ca -> hbf
  ln_fused<<<dim3(T_), 256, 0, stream>>>(x1, hbf, bo_ca, ln3_g, ln3_b, hbf, x2);

  // --- FFN block ---
  gemm_bt<2><<<dim3(4096 / 128, T_ / 128), 256, 0, stream>>>(
      hbf, w1_t, b1, ffn, T_, 4096, 1024);
  gemm_bt64<<<dim3(1024 / 128, T_ / 64), 256, 0, stream>>>(
      ffn, w2_t, hbf, T_, 1024, 4096);                          // delta_ffn -> hbf
  addbias<<<dim3((T_ * 1024) / (256 * 4)), 256, 0, stream>>>(
      x2, hbf, b2, (float*)d_out);
}